// Round 8
// baseline (124.744 us; speedup 1.0000x reference)
//
#include <hip/hip_runtime.h>

#define FSZ 5

// Problem constants (from reference setup_inputs)
#define B_ 2
#define C_ 64
#define H_ 256
#define W_ 256
#define HIN (H_ + FSZ - 1)   // 260
#define WIN (W_ + FSZ - 1)   // 260
#define PLANE (HIN * WIN)    // 67600 pixels per (b,c) plane

#define PXB 32               // pixels per gather block (R5 proven shape)
#define NXG (W_ / PXB)       // 8 x-groups per row
#define CG  8                // channel groups per pixel (8 ch each)

// round-to-nearest-even f32 -> bf16
__device__ __forceinline__ unsigned bf16r(float f) {
    unsigned u = __float_as_uint(f);
    return (u + 0x7fffu + ((u >> 16) & 1u)) >> 16;
}

// uniform-base + u32 byte-offset load (emits saddr-form global_load)
__device__ __forceinline__ float ldf(const float* __restrict__ base, unsigned byteOff) {
    return *(const float*)((const char*)base + byteOff);
}

// ---------------------------------------------------------------------------
// Kernel A: transpose+narrow [b][c][y][x] f32 -> ws[b][(y,x)][c] bf16.
// (proven R5, ~12us)
// ---------------------------------------------------------------------------
__global__ __launch_bounds__(256) void transpose_bf16_kernel(
    const float* __restrict__ inp, unsigned* __restrict__ wsu)
{
    __shared__ float t[64][65];            // +1 pad
    const int NP64 = (PLANE + 63) / 64;    // 1057 pixel tiles
    int bid = blockIdx.x;
    const int b  = bid / NP64;
    const int p0 = (bid % NP64) * 64;
    const float* ib = inp + (size_t)b * C_ * PLANE;
    unsigned*    wb = wsu + (size_t)b * PLANE * (C_ / 2);
    const int tid = threadIdx.x;

    #pragma unroll
    for (int it = 0; it < 16; ++it) {
        const int e = it * 256 + tid;
        const int c = e >> 6;              // 0..63
        const int p = e & 63;              // 0..63
        const int pp = p0 + p;
        t[p][c] = (pp < PLANE) ? ib[(size_t)c * PLANE + pp] : 0.f;
    }
    __syncthreads();
    #pragma unroll
    for (int it = 0; it < 8; ++it) {
        const int e = it * 256 + tid;      // 0..2047
        const int c2 = e & 31;             // uint-channel 0..31
        const int p  = e >> 5;             // 0..63
        const int pp = p0 + p;
        if (pp < PLANE) {
            const unsigned v = bf16r(t[p][2 * c2]) | (bf16r(t[p][2 * c2 + 1]) << 16);
            wb[(size_t)pp * (C_ / 2) + c2] = v;
        }
    }
}

// ---------------------------------------------------------------------------
// Kernel B: gather from bf16 channels-last ws (R5 shape: 8 ch/thread,
// VGPR~40, occ~55%) + all addresses as u32 byte offsets from uniform bases.
// ---------------------------------------------------------------------------
#define BLO(u) __uint_as_float((u) << 16)
#define BHI(u) __uint_as_float((u) & 0xffff0000u)
#define ACC8(U, Wt) \
    a0 = fmaf(Wt, BLO(U.x), a0); a1 = fmaf(Wt, BHI(U.x), a1); \
    a2 = fmaf(Wt, BLO(U.y), a2); a3 = fmaf(Wt, BHI(U.y), a3); \
    a4 = fmaf(Wt, BLO(U.z), a4); a5 = fmaf(Wt, BHI(U.z), a5); \
    a6 = fmaf(Wt, BLO(U.w), a6); a7 = fmaf(Wt, BHI(U.w), a7);

__global__ __launch_bounds__(256) void dsepconv_bf16_kernel(
    const char* __restrict__ wsc,
    const float* __restrict__ vertical,
    const float* __restrict__ horizontal,
    const float* __restrict__ offx,
    const float* __restrict__ offy,
    const float* __restrict__ mask,
    float* __restrict__ out)
{
    const int t  = threadIdx.x;
    const int cg = t & (CG - 1);           // 0..7 -> channels cg*8..cg*8+7
    const int pl = t >> 3;                 // 0..31
    int bid = blockIdx.x;
    const int xg = bid % NXG; bid /= NXG;
    const int y  = bid % H_;  bid /= H_;
    const int b  = bid;
    const int x  = xg * PXB + pl;

    const int HW  = H_ * W_;
    const unsigned HW4 = (unsigned)HW * 4u;
    const int pix = y * W_ + x;

    // u32 byte offsets from uniform kernel-arg bases (saddr-form loads)
    const unsigned vOff = ((unsigned)(b * FSZ) * (unsigned)HW + (unsigned)pix) * 4u;
    const unsigned pOff = ((unsigned)(b * FSZ * FSZ) * (unsigned)HW + (unsigned)pix) * 4u;
    // channels-last ws: per-thread base offset (pixel stride 128B, cg*16B)
    const unsigned wBase = (unsigned)b * (unsigned)(PLANE * 128) + (unsigned)cg * 16u;

    float a0=0.f,a1=0.f,a2=0.f,a3=0.f,a4=0.f,a5=0.f,a6=0.f,a7=0.f;

    float hj_r[FSZ];
    #pragma unroll
    for (int j = 0; j < FSZ; ++j) hj_r[j] = ldf(horizontal, vOff + (unsigned)j * HW4);

    for (int i = 0; i < FSZ; ++i) {
        const float vi = ldf(vertical, vOff + (unsigned)i * HW4);
        const float yi = (float)(y + i);
        #pragma unroll
        for (int j = 0; j < FSZ; ++j) {
            const unsigned kOff = pOff + (unsigned)(i * FSZ + j) * HW4;
            const float offy_v = ldf(offy, kOff);
            const float offx_v = ldf(offx, kOff);
            const float m_v    = ldf(mask, kOff);

            const float pyf = yi + offy_v;
            const float pxf = (float)(x + j) + offx_v;
            const float y0f = floorf(pyf);
            const float x0f = floorf(pxf);
            const float ay = pyf - y0f;
            const float ax = pxf - x0f;

            int y0 = (int)y0f;
            int x0 = (int)x0f;
            int y1 = y0 + 1;
            int x1 = x0 + 1;
            y0 = min(max(y0, 0), HIN - 1);
            y1 = min(max(y1, 0), HIN - 1);
            x0 = min(max(x0, 0), WIN - 1);
            x1 = min(max(x1, 0), WIN - 1);

            const float w   = vi * hj_r[j] * m_v;
            const float w00 = w * (1.f - ay) * (1.f - ax);
            const float w01 = w * (1.f - ay) * ax;
            const float w10 = w * ay * (1.f - ax);
            const float w11 = w * ay * ax;

            // u32 byte offsets into the bf16 channels-last plane
            const unsigned o00 = wBase + (unsigned)(y0 * WIN + x0) * 128u;
            const unsigned o01 = wBase + (unsigned)(y0 * WIN + x1) * 128u;
            const unsigned o10 = wBase + (unsigned)(y1 * WIN + x0) * 128u;
            const unsigned o11 = wBase + (unsigned)(y1 * WIN + x1) * 128u;

            const uint4 u00 = *(const uint4*)(wsc + o00);
            const uint4 u01 = *(const uint4*)(wsc + o01);
            const uint4 u10 = *(const uint4*)(wsc + o10);
            const uint4 u11 = *(const uint4*)(wsc + o11);

            ACC8(u00, w00);
            ACC8(u01, w01);
            ACC8(u10, w10);
            ACC8(u11, w11);
        }
    }

    // output is channels-first [b][c][y][x]
    float* outp = out + (size_t)(b * C_ + cg * 8) * HW + pix;
    outp[0 * HW] = a0;
    outp[1 * HW] = a1;
    outp[2 * HW] = a2;
    outp[3 * HW] = a3;
    outp[4 * HW] = a4;
    outp[5 * HW] = a5;
    outp[6 * HW] = a6;
    outp[7 * HW] = a7;
}

// ---------------------------------------------------------------------------
// Fallback (R1, proven-correct, ~613us): channels-first scattered gather.
// ---------------------------------------------------------------------------
#define CHUNK 16
__global__ __launch_bounds__(256) void dsepconv_kernel(
    const float* __restrict__ inp,
    const float* __restrict__ vertical,
    const float* __restrict__ horizontal,
    const float* __restrict__ offx,
    const float* __restrict__ offy,
    const float* __restrict__ mask,
    float* __restrict__ out)
{
    const int NCH = C_ / CHUNK;
    const int x = threadIdx.x;
    int bid = blockIdx.x;
    const int cc = bid % NCH; bid /= NCH;
    const int y  = bid % H_;  bid /= H_;
    const int b  = bid;
    const int c0 = cc * CHUNK;

    const int HW = H_ * W_;
    const int pix = y * W_ + x;

    const float* vert = vertical   + (size_t)(b * FSZ) * HW + pix;
    const float* horz = horizontal + (size_t)(b * FSZ) * HW + pix;
    const float* ox   = offx + (size_t)(b * FSZ * FSZ) * HW + pix;
    const float* oy   = offy + (size_t)(b * FSZ * FSZ) * HW + pix;
    const float* mk   = mask + (size_t)(b * FSZ * FSZ) * HW + pix;
    const float* inb  = inp + (size_t)(b * C_ + c0) * PLANE;

    float acc[CHUNK];
    #pragma unroll
    for (int c = 0; c < CHUNK; ++c) acc[c] = 0.f;

    float hj_r[FSZ];
    #pragma unroll
    for (int j = 0; j < FSZ; ++j) hj_r[j] = horz[j * HW];

    for (int i = 0; i < FSZ; ++i) {
        const float vi = vert[i * HW];
        #pragma unroll
        for (int j = 0; j < FSZ; ++j) {
            const int k = i * FSZ + j;
            const float offy_v = oy[k * HW];
            const float offx_v = ox[k * HW];
            const float m_v    = mk[k * HW];

            const float pyf = (float)(y + i) + offy_v;
            const float pxf = (float)(x + j) + offx_v;
            const float y0f = floorf(pyf);
            const float x0f = floorf(pxf);
            const float ay = pyf - y0f;
            const float ax = pxf - x0f;

            int y0 = (int)y0f;
            int x0 = (int)x0f;
            int y1 = y0 + 1;
            int x1 = x0 + 1;
            y0 = min(max(y0, 0), HIN - 1);
            y1 = min(max(y1, 0), HIN - 1);
            x0 = min(max(x0, 0), WIN - 1);
            x1 = min(max(x1, 0), WIN - 1);

            const float w   = vi * hj_r[j] * m_v;
            const float w00 = w * (1.f - ay) * (1.f - ax);
            const float w01 = w * (1.f - ay) * ax;
            const float w10 = w * ay * (1.f - ax);
            const float w11 = w * ay * ax;

            const int i00 = y0 * WIN + x0;
            const int i01 = y0 * WIN + x1;
            const int i10 = y1 * WIN + x0;
            const int i11 = y1 * WIN + x1;

            #pragma unroll
            for (int c = 0; c < CHUNK; ++c) {
                const float* p = inb + (size_t)c * PLANE;
                float a = acc[c];
                a = fmaf(w00, p[i00], a);
                a = fmaf(w01, p[i01], a);
                a = fmaf(w10, p[i10], a);
                a = fmaf(w11, p[i11], a);
                acc[c] = a;
            }
        }
    }

    float* outp = out + (size_t)(b * C_ + c0) * HW + pix;
    #pragma unroll
    for (int c = 0; c < CHUNK; ++c)
        outp[(size_t)c * HW] = acc[c];
}

extern "C" void kernel_launch(void* const* d_in, const int* in_sizes, int n_in,
                              void* d_out, int out_size, void* d_ws, size_t ws_size,
                              hipStream_t stream) {
    const float* inp        = (const float*)d_in[0];
    const float* vertical   = (const float*)d_in[1];
    const float* horizontal = (const float*)d_in[2];
    const float* offset_x   = (const float*)d_in[3];
    const float* offset_y   = (const float*)d_in[4];
    const float* mask       = (const float*)d_in[5];
    float* out              = (float*)d_out;

    const size_t need = (size_t)B_ * PLANE * C_ * sizeof(unsigned short); // 17.3 MB

    if (ws_size >= need) {
        const int NP64 = (PLANE + 63) / 64;
        transpose_bf16_kernel<<<dim3(B_ * NP64), dim3(256), 0, stream>>>(
            inp, (unsigned*)d_ws);
        dsepconv_bf16_kernel<<<dim3(B_ * H_ * NXG), dim3(256), 0, stream>>>(
            (const char*)d_ws, vertical, horizontal, offset_x, offset_y, mask, out);
    } else {
        const int NCH = C_ / CHUNK;
        dsepconv_kernel<<<dim3(B_ * H_ * NCH), dim3(W_), 0, stream>>>(
            inp, vertical, horizontal, offset_x, offset_y, mask, out);
    }
}

// Round 9
// 96.903 us; speedup vs baseline: 1.2873x; 1.2873x over previous
//
#include <hip/hip_runtime.h>

#define FSZ 5

// Problem constants (from reference setup_inputs)
#define B_ 2
#define C_ 64
#define H_ 256
#define W_ 256
#define HIN (H_ + FSZ - 1)   // 260
#define WIN (W_ + FSZ - 1)   // 260
#define PLANE (HIN * WIN)    // 67600 pixels per (b,c) plane

#define PXB 32               // pixels per gather block (R5 proven shape)
#define NXG (W_ / PXB)       // 8 x-groups per row
#define CG  8                // channel groups per pixel (8 ch each)

typedef float v2f __attribute__((ext_vector_type(2)));

// round-to-nearest-even f32 -> bf16
__device__ __forceinline__ unsigned bf16r(float f) {
    unsigned u = __float_as_uint(f);
    return (u + 0x7fffu + ((u >> 16) & 1u)) >> 16;
}

// unpack one u32 (2 packed bf16) into a float2 {even_ch, odd_ch}
__device__ __forceinline__ v2f unpk(unsigned u) {
    v2f r;
    r.x = __uint_as_float(u << 16);
    r.y = __uint_as_float(u & 0xffff0000u);
    return r;
}

// ---------------------------------------------------------------------------
// Kernel A: transpose+narrow [b][c][y][x] f32 -> ws[b][(y,x)][c] bf16.
// (proven R5, ~12us)
// ---------------------------------------------------------------------------
__global__ __launch_bounds__(256) void transpose_bf16_kernel(
    const float* __restrict__ inp, unsigned* __restrict__ wsu)
{
    __shared__ float t[64][65];            // +1 pad
    const int NP64 = (PLANE + 63) / 64;    // 1057 pixel tiles
    int bid = blockIdx.x;
    const int b  = bid / NP64;
    const int p0 = (bid % NP64) * 64;
    const float* ib = inp + (size_t)b * C_ * PLANE;
    unsigned*    wb = wsu + (size_t)b * PLANE * (C_ / 2);
    const int tid = threadIdx.x;

    #pragma unroll
    for (int it = 0; it < 16; ++it) {
        const int e = it * 256 + tid;
        const int c = e >> 6;              // 0..63
        const int p = e & 63;              // 0..63
        const int pp = p0 + p;
        t[p][c] = (pp < PLANE) ? ib[(size_t)c * PLANE + pp] : 0.f;
    }
    __syncthreads();
    #pragma unroll
    for (int it = 0; it < 8; ++it) {
        const int e = it * 256 + tid;      // 0..2047
        const int c2 = e & 31;             // uint-channel 0..31
        const int p  = e >> 5;             // 0..63
        const int pp = p0 + p;
        if (pp < PLANE) {
            const unsigned v = bf16r(t[p][2 * c2]) | (bf16r(t[p][2 * c2 + 1]) << 16);
            wb[(size_t)pp * (C_ / 2) + c2] = v;
        }
    }
}

// ---------------------------------------------------------------------------
// Kernel B: gather from bf16 channels-last ws — VERBATIM R5 structure
// (8 ch/thread, VGPR~40, occ~55%, gather ~117us), with ONE change:
// float2 accumulators + __builtin_elementwise_fma so clang can select
// v_pk_fma_f32 (halves FMA issue count, no register-pressure change).
// ---------------------------------------------------------------------------
#define ACC8(U, Wt) do {                                        \
    const v2f wv = {Wt, Wt};                                    \
    acc0 = __builtin_elementwise_fma(wv, unpk(U.x), acc0);      \
    acc1 = __builtin_elementwise_fma(wv, unpk(U.y), acc1);      \
    acc2 = __builtin_elementwise_fma(wv, unpk(U.z), acc2);      \
    acc3 = __builtin_elementwise_fma(wv, unpk(U.w), acc3);      \
} while (0)

__global__ __launch_bounds__(256) void dsepconv_bf16_kernel(
    const uint4* __restrict__ wsq,
    const float* __restrict__ vertical,
    const float* __restrict__ horizontal,
    const float* __restrict__ offx,
    const float* __restrict__ offy,
    const float* __restrict__ mask,
    float* __restrict__ out)
{
    const int t  = threadIdx.x;
    const int cg = t & (CG - 1);           // 0..7 -> channels cg*8..cg*8+7
    const int pl = t >> 3;                 // 0..31
    int bid = blockIdx.x;
    const int xg = bid % NXG; bid /= NXG;
    const int y  = bid % H_;  bid /= H_;
    const int b  = bid;
    const int x  = xg * PXB + pl;

    const int HW = H_ * W_;
    const int pix = y * W_ + x;

    const float* vert = vertical   + (size_t)(b * FSZ) * HW + pix;
    const float* horz = horizontal + (size_t)(b * FSZ) * HW + pix;
    const float* ox   = offx + (size_t)(b * FSZ * FSZ) * HW + pix;
    const float* oy   = offy + (size_t)(b * FSZ * FSZ) * HW + pix;
    const float* mk   = mask + (size_t)(b * FSZ * FSZ) * HW + pix;
    // per-pixel = 8 uint4s; this thread's channel group adds +cg
    const uint4* wsb  = wsq + (size_t)b * PLANE * CG + cg;

    v2f acc0 = {0.f, 0.f}, acc1 = {0.f, 0.f},
        acc2 = {0.f, 0.f}, acc3 = {0.f, 0.f};

    float hj_r[FSZ];
    #pragma unroll
    for (int j = 0; j < FSZ; ++j) hj_r[j] = horz[j * HW];

    for (int i = 0; i < FSZ; ++i) {
        const float vi = vert[i * HW];
        #pragma unroll
        for (int j = 0; j < FSZ; ++j) {
            const int k = i * FSZ + j;
            const float offy_v = oy[k * HW];
            const float offx_v = ox[k * HW];
            const float m_v    = mk[k * HW];

            const float pyf = (float)(y + i) + offy_v;
            const float pxf = (float)(x + j) + offx_v;
            const float y0f = floorf(pyf);
            const float x0f = floorf(pxf);
            const float ay = pyf - y0f;
            const float ax = pxf - x0f;

            int y0 = (int)y0f;
            int x0 = (int)x0f;
            int y1 = y0 + 1;
            int x1 = x0 + 1;
            y0 = min(max(y0, 0), HIN - 1);
            y1 = min(max(y1, 0), HIN - 1);
            x0 = min(max(x0, 0), WIN - 1);
            x1 = min(max(x1, 0), WIN - 1);

            const float w   = vi * hj_r[j] * m_v;
            const float w00 = w * (1.f - ay) * (1.f - ax);
            const float w01 = w * (1.f - ay) * ax;
            const float w10 = w * ay * (1.f - ax);
            const float w11 = w * ay * ax;

            const uint4 u00 = wsb[(size_t)(y0 * WIN + x0) * CG];
            const uint4 u01 = wsb[(size_t)(y0 * WIN + x1) * CG];
            const uint4 u10 = wsb[(size_t)(y1 * WIN + x0) * CG];
            const uint4 u11 = wsb[(size_t)(y1 * WIN + x1) * CG];

            ACC8(u00, w00);
            ACC8(u01, w01);
            ACC8(u10, w10);
            ACC8(u11, w11);
        }
    }

    // output is channels-first [b][c][y][x]; acc0={c0,c1}, acc1={c2,c3}, ...
    float* outp = out + (size_t)(b * C_ + cg * 8) * HW + pix;
    outp[0 * HW] = acc0.x;
    outp[1 * HW] = acc0.y;
    outp[2 * HW] = acc1.x;
    outp[3 * HW] = acc1.y;
    outp[4 * HW] = acc2.x;
    outp[5 * HW] = acc2.y;
    outp[6 * HW] = acc3.x;
    outp[7 * HW] = acc3.y;
}

// ---------------------------------------------------------------------------
// Fallback (R1, proven-correct, ~613us): channels-first scattered gather.
// ---------------------------------------------------------------------------
#define CHUNK 16
__global__ __launch_bounds__(256) void dsepconv_kernel(
    const float* __restrict__ inp,
    const float* __restrict__ vertical,
    const float* __restrict__ horizontal,
    const float* __restrict__ offx,
    const float* __restrict__ offy,
    const float* __restrict__ mask,
    float* __restrict__ out)
{
    const int NCH = C_ / CHUNK;
    const int x = threadIdx.x;
    int bid = blockIdx.x;
    const int cc = bid % NCH; bid /= NCH;
    const int y  = bid % H_;  bid /= H_;
    const int b  = bid;
    const int c0 = cc * CHUNK;

    const int HW = H_ * W_;
    const int pix = y * W_ + x;

    const float* vert = vertical   + (size_t)(b * FSZ) * HW + pix;
    const float* horz = horizontal + (size_t)(b * FSZ) * HW + pix;
    const float* ox   = offx + (size_t)(b * FSZ * FSZ) * HW + pix;
    const float* oy   = offy + (size_t)(b * FSZ * FSZ) * HW + pix;
    const float* mk   = mask + (size_t)(b * FSZ * FSZ) * HW + pix;
    const float* inb  = inp + (size_t)(b * C_ + c0) * PLANE;

    float acc[CHUNK];
    #pragma unroll
    for (int c = 0; c < CHUNK; ++c) acc[c] = 0.f;

    float hj_r[FSZ];
    #pragma unroll
    for (int j = 0; j < FSZ; ++j) hj_r[j] = horz[j * HW];

    for (int i = 0; i < FSZ; ++i) {
        const float vi = vert[i * HW];
        #pragma unroll
        for (int j = 0; j < FSZ; ++j) {
            const int k = i * FSZ + j;
            const float offy_v = oy[k * HW];
            const float offx_v = ox[k * HW];
            const float m_v    = mk[k * HW];

            const float pyf = (float)(y + i) + offy_v;
            const float pxf = (float)(x + j) + offx_v;
            const float y0f = floorf(pyf);
            const float x0f = floorf(pxf);
            const float ay = pyf - y0f;
            const float ax = pxf - x0f;

            int y0 = (int)y0f;
            int x0 = (int)x0f;
            int y1 = y0 + 1;
            int x1 = x0 + 1;
            y0 = min(max(y0, 0), HIN - 1);
            y1 = min(max(y1, 0), HIN - 1);
            x0 = min(max(x0, 0), WIN - 1);
            x1 = min(max(x1, 0), WIN - 1);

            const float w   = vi * hj_r[j] * m_v;
            const float w00 = w * (1.f - ay) * (1.f - ax);
            const float w01 = w * (1.f - ay) * ax;
            const float w10 = w * ay * (1.f - ax);
            const float w11 = w * ay * ax;

            const int i00 = y0 * WIN + x0;
            const int i01 = y0 * WIN + x1;
            const int i10 = y1 * WIN + x0;
            const int i11 = y1 * WIN + x1;

            #pragma unroll
            for (int c = 0; c < CHUNK; ++c) {
                const float* p = inb + (size_t)c * PLANE;
                float a = acc[c];
                a = fmaf(w00, p[i00], a);
                a = fmaf(w01, p[i01], a);
                a = fmaf(w10, p[i10], a);
                a = fmaf(w11, p[i11], a);
                acc[c] = a;
            }
        }
    }

    float* outp = out + (size_t)(b * C_ + c0) * HW + pix;
    #pragma unroll
    for (int c = 0; c < CHUNK; ++c)
        outp[(size_t)c * HW] = acc[c];
}

extern "C" void kernel_launch(void* const* d_in, const int* in_sizes, int n_in,
                              void* d_out, int out_size, void* d_ws, size_t ws_size,
                              hipStream_t stream) {
    const float* inp        = (const float*)d_in[0];
    const float* vertical   = (const float*)d_in[1];
    const float* horizontal = (const float*)d_in[2];
    const float* offset_x   = (const float*)d_in[3];
    const float* offset_y   = (const float*)d_in[4];
    const float* mask       = (const float*)d_in[5];
    float* out              = (float*)d_out;

    const size_t need = (size_t)B_ * PLANE * C_ * sizeof(unsigned short); // 17.3 MB

    if (ws_size >= need) {
        const int NP64 = (PLANE + 63) / 64;
        transpose_bf16_kernel<<<dim3(B_ * NP64), dim3(256), 0, stream>>>(
            inp, (unsigned*)d_ws);
        dsepconv_bf16_kernel<<<dim3(B_ * H_ * NXG), dim3(256), 0, stream>>>(
            (const uint4*)d_ws, vertical, horizontal, offset_x, offset_y, mask, out);
    } else {
        const int NCH = C_ / CHUNK;
        dsepconv_kernel<<<dim3(B_ * H_ * NCH), dim3(W_), 0, stream>>>(
            inp, vertical, horizontal, offset_x, offset_y, mask, out);
    }
}